// Round 1
// baseline (264.275 us; speedup 1.0000x reference)
//
#include <hip/hip_runtime.h>
#include <cstdint>

// GraphormerMultiHeadAttention on MI355X (gfx950), bf16 MFMA path.
// B=16, N=512, D=1024, H=16, hd=64. scale = D^-0.5 = 1/32.
//
// R3 -> R4 changes:
//  - qkv/oproj epilogues: Q/K/O computed TRANSPOSED (mfma operand swap) so
//    per-lane accumulator regs index the output-contiguous dim (hd / gn).
//    Q/K: 64 scalar 2B stores -> 16 ushort4 stores; O: 64x4B -> 16 float4.
//    (WRITE_SIZE 64.8MB -> ~52MB predicted, fewer epilogue VALU ops.)
//  - attn: T3 2-phase double-buffered K/V staging. Stage tile j+1 BEFORE
//    computing tile j; raw s_barrier + counted `s_waitcnt vmcnt(4)` instead
//    of __syncthreads (which drains vmcnt(0) and serialized the staging
//    latency every iteration). Q fragments hoisted out of the j-loop.
//    setprio(1) around MFMA clusters.

typedef unsigned short u16;
typedef unsigned int   u32;
typedef __attribute__((ext_vector_type(8))) short bf8;   // 8 x bf16 (4 VGPRs)
typedef __attribute__((ext_vector_type(4))) float f4;    // 4 x f32 accum

__device__ __forceinline__ u16 f2bf(float x) {
  u32 u = __float_as_uint(x);
  u += 0x7FFF + ((u >> 16) & 1);        // round-to-nearest-even
  return (u16)(u >> 16);
}

__device__ __forceinline__ float bf2f(u16 x) {
  return __uint_as_float(((u32)x) << 16);
}

// async global->LDS, 16B per lane. LDS dest = wave-uniform base + lane*16.
__device__ __forceinline__ void gl2lds16(const void* g, void* l) {
  __builtin_amdgcn_global_load_lds(
      (const __attribute__((address_space(1))) u32*)g,
      (__attribute__((address_space(3))) u32*)l, 16, 0, 0);
}

// raw workgroup barrier WITHOUT the __syncthreads vmcnt(0) drain.
// compile-time memory fences stop LLVM from moving memory ops across it.
__device__ __forceinline__ void barrier_raw() {
  asm volatile("" ::: "memory");
  __builtin_amdgcn_s_barrier();
  asm volatile("" ::: "memory");
}

// ---------------- cast kernels ----------------

__global__ __launch_bounds__(256) void cast_bf16(const float* __restrict__ src,
                                                 uint4* __restrict__ dst, int n8) {
  const int i = blockIdx.x * 256 + threadIdx.x;
  if (i >= n8) return;
  const float4* s = (const float4*)src;
  const float4 a = s[2 * i], c = s[2 * i + 1];
  uint4 o;
  o.x = (u32)f2bf(a.x) | ((u32)f2bf(a.y) << 16);
  o.y = (u32)f2bf(a.z) | ((u32)f2bf(a.w) << 16);
  o.z = (u32)f2bf(c.x) | ((u32)f2bf(c.y) << 16);
  o.w = (u32)f2bf(c.z) | ((u32)f2bf(c.w) << 16);
  dst[i] = o;
}

// 4 weight matrices (1M elems each) in one launch: i>>17 selects the matrix.
__global__ __launch_bounds__(256) void cast4_bf16(
    const float* __restrict__ s0, const float* __restrict__ s1,
    const float* __restrict__ s2, const float* __restrict__ s3,
    uint4* __restrict__ d0, uint4* __restrict__ d1,
    uint4* __restrict__ d2, uint4* __restrict__ d3) {
  const int i = blockIdx.x * 256 + threadIdx.x;     // 0 .. 524287
  const int w = i >> 17, j = i & 131071;
  const float* src = (w == 0) ? s0 : (w == 1) ? s1 : (w == 2) ? s2 : s3;
  uint4* dst = (w == 0) ? d0 : (w == 1) ? d1 : (w == 2) ? d2 : d3;
  const float4* s = (const float4*)src;
  const float4 a = s[2 * j], c = s[2 * j + 1];
  uint4 o;
  o.x = (u32)f2bf(a.x) | ((u32)f2bf(a.y) << 16);
  o.y = (u32)f2bf(a.z) | ((u32)f2bf(a.w) << 16);
  o.z = (u32)f2bf(c.x) | ((u32)f2bf(c.y) << 16);
  o.w = (u32)f2bf(c.z) | ((u32)f2bf(c.w) << 16);
  dst[j] = o;
}

// bias = bf16(sp+ed), permuted so attn lane `tid` of block (b, qt, jt) reads
// its 16 values (4 rows x 4 col-groups) as one contiguous 32B chunk.
// chunk element order: idx = nb*4 + r  (nb = col group, r = row within quad)
__global__ __launch_bounds__(256) void bias_perm(const float* __restrict__ sp,
                                                 const float* __restrict__ ed,
                                                 u16* __restrict__ Bp) {
  const int jt = blockIdx.x, qt = blockIdx.y, b = blockIdx.z;
  const int tid = threadIdx.x;
  const int wave = tid >> 6, quad = (tid >> 4) & 3, l16 = tid & 15;
  const int qrl = (wave << 4) + (quad << 2);
  union { u16 a[16]; uint4 v[2]; } tmp;
#pragma unroll
  for (int nb = 0; nb < 4; nb++) {
    const int col = (jt << 6) + (nb << 4) + l16;
#pragma unroll
    for (int r = 0; r < 4; r++) {
      const int row = (qt << 6) + qrl + r;
      const size_t idx = ((size_t)b << 18) + (size_t)row * 512 + col;
      tmp.a[nb * 4 + r] = f2bf(sp[idx] + ed[idx]);
    }
  }
  uint4* out = (uint4*)Bp + ((((size_t)b * 8 + qt) * 8 + jt) * 256 + tid) * 2;
  out[0] = tmp.v[0];
  out[1] = tmp.v[1];
}

// ---------------- GEMM core: C(128x128) = A(128x1024) * Bt(128x1024)^T ----------------
// A row-major [M][1024], Bt row-major [Nout][1024] (computes A @ Bt^T).
// LDS tiles are [128 rows][8 chunks of 16B], slot (r,c) holds global chunk c^(r&7).
// SWAP=true computes C^T fragments (mfma(B,A)): lane&15 -> M dim, (quad,reg) -> N
// dim, so the 4 regs of each fragment are CONSECUTIVE along N -> packed stores.

template <bool SWAP>
__device__ __forceinline__ void gemm_core(const u16* __restrict__ A,
                                          const u16* __restrict__ Bt,
                                          int m0, int n0,
                                          u16* lA, u16* lB, f4 acc[4][4]) {
  const int tid  = threadIdx.x;
  const int wave = tid >> 6;
  const int lane = tid & 63;
  const int quad = lane >> 4;
  const int l16  = lane & 15;
  const int wm   = (wave >> 1) << 6;
  const int wn   = (wave & 1) << 6;
  const int srow = tid >> 3;
  const int scol = ((tid & 7) ^ (srow & 7)) << 3;   // swizzled source chunk
  const int c0   = (quad ^ (l16 & 7)) << 3;         // swizzled read offset, kk=0

  f4 zero = {0.f, 0.f, 0.f, 0.f};
#pragma unroll
  for (int mi = 0; mi < 4; mi++)
#pragma unroll
    for (int ni = 0; ni < 4; ni++) acc[mi][ni] = zero;

  const u16* Ab = A  + (size_t)(m0 + srow) * 1024 + scol;
  const u16* Bb = Bt + (size_t)(n0 + srow) * 1024 + scol;

  for (int k0 = 0; k0 < 1024; k0 += 64) {
    __syncthreads();   // protect LDS from previous iteration's readers
#pragma unroll
    for (int i = 0; i < 4; i++) {
      gl2lds16(Ab + (size_t)(i << 5) * 1024 + k0,
               (char*)lA + (((i << 8) + (wave << 6)) << 4));
      gl2lds16(Bb + (size_t)(i << 5) * 1024 + k0,
               (char*)lB + (((i << 8) + (wave << 6)) << 4));
    }
    __syncthreads();   // drains vmcnt(0) -> tiles visible
#pragma unroll
    for (int kk = 0; kk < 64; kk += 32) {
      const int o = c0 ^ kk;
      bf8 af[4], bfr[4];
#pragma unroll
      for (int mi = 0; mi < 4; mi++)
        af[mi] = *(const bf8*)(lA + (wm + (mi << 4) + l16) * 64 + o);
#pragma unroll
      for (int ni = 0; ni < 4; ni++)
        bfr[ni] = *(const bf8*)(lB + (wn + (ni << 4) + l16) * 64 + o);
#pragma unroll
      for (int mi = 0; mi < 4; mi++)
#pragma unroll
        for (int ni = 0; ni < 4; ni++) {
          if (SWAP)
            acc[mi][ni] = __builtin_amdgcn_mfma_f32_16x16x32_bf16(
                bfr[ni], af[mi], acc[mi][ni], 0, 0, 0);
          else
            acc[mi][ni] = __builtin_amdgcn_mfma_f32_16x16x32_bf16(
                af[mi], bfr[ni], acc[mi][ni], 0, 0, 0);
        }
    }
  }
}

// ---------------- QKV projection ----------------
// XCD remap: flat bits [2:0]=m_lo [5:3]=n_tile [8:6]=m_hi [10:9]=proj.

__global__ __launch_bounds__(256) void qkv_kernel(
    const u16* __restrict__ xb, const u16* __restrict__ wq,
    const u16* __restrict__ wk, const u16* __restrict__ wv,
    u16* __restrict__ Qh, u16* __restrict__ Kh, u16* __restrict__ Vt) {
  __shared__ __align__(16) u16 lA[128 * 64];
  __shared__ __align__(16) u16 lB[128 * 64];
  const int flat = blockIdx.x + (blockIdx.y << 3) + (blockIdx.z << 9);
  const int m_tile = (flat & 7) | (((flat >> 6) & 7) << 3);
  const int n_tile = (flat >> 3) & 7;
  const int proj = flat >> 9;
  const int m0 = m_tile << 7, n0 = n_tile << 7;
  const u16* W = (proj == 0) ? wq : (proj == 1) ? wk : wv;

  const int tid = threadIdx.x, wave = tid >> 6, lane = tid & 63;
  const int quad = lane >> 4, l16 = lane & 15;
  const int wm = (wave >> 1) << 6, wn = (wave & 1) << 6;
  f4 acc[4][4];

  if (proj == 2) {
    // V: normal orientation; C rows (quad,reg) = tokens, which are the
    // contiguous dim of Vt [B,H,hd,512] -> ushort4 over 4 consecutive n.
    gemm_core<false>(xb, W, m0, n0, lA, lB, acc);
#pragma unroll
    for (int mi = 0; mi < 4; mi++) {
      const int gmb = m0 + wm + (mi << 4) + (quad << 2);
      const int b = gmb >> 9, nb = gmb & 511;
#pragma unroll
      for (int ni = 0; ni < 4; ni++) {
        const int gn = n0 + wn + (ni << 4) + l16;
        const int h = gn >> 6, hdi = gn & 63;
        ushort4 pk;
        pk.x = f2bf(acc[mi][ni][0]);
        pk.y = f2bf(acc[mi][ni][1]);
        pk.z = f2bf(acc[mi][ni][2]);
        pk.w = f2bf(acc[mi][ni][3]);
        *(ushort4*)(Vt + ((size_t)((b << 4) + h) * 64 + hdi) * 512 + nb) = pk;
      }
    }
  } else {
    // Q/K: transposed fragments; (quad,reg) = hd (contiguous in Qh/Kh),
    // lane&15 = token row -> one ushort4 per fragment.
    gemm_core<true>(xb, W, m0, n0, lA, lB, acc);
    u16* dst = (proj == 0) ? Qh : Kh;
#pragma unroll
    for (int mi = 0; mi < 4; mi++) {
      const int gm = m0 + wm + (mi << 4) + l16;      // token row
      const int b = gm >> 9, n = gm & 511;
#pragma unroll
      for (int ni = 0; ni < 4; ni++) {
        const int gn = n0 + wn + (ni << 4) + (quad << 2);  // hd dim
        const int h = gn >> 6, hdi = gn & 63;
        ushort4 pk;
        pk.x = f2bf(acc[mi][ni][0]);
        pk.y = f2bf(acc[mi][ni][1]);
        pk.z = f2bf(acc[mi][ni][2]);
        pk.w = f2bf(acc[mi][ni][3]);
        *(ushort4*)(dst + ((size_t)((b << 4) + h) * 512 + n) * 64 + hdi) = pk;
      }
    }
  }
}

// ---------------- output projection ----------------
// XCD remap: flat bits [2:0]=m_lo [5:3]=n_tile [8:6]=m_hi.
// Transposed fragments -> float4 stores (gn contiguous).

__global__ __launch_bounds__(256) void oproj_kernel(const u16* __restrict__ Ob,
                                                    const u16* __restrict__ wo,
                                                    float* __restrict__ out) {
  __shared__ __align__(16) u16 lA[128 * 64];
  __shared__ __align__(16) u16 lB[128 * 64];
  const int flat = blockIdx.x + (blockIdx.y << 3);
  const int m0 = ((flat & 7) | (((flat >> 6) & 7) << 3)) << 7;
  const int n0 = ((flat >> 3) & 7) << 7;
  f4 acc[4][4];
  gemm_core<true>(Ob, wo, m0, n0, lA, lB, acc);

  const int tid = threadIdx.x, wave = tid >> 6, lane = tid & 63;
  const int quad = lane >> 4, l16 = lane & 15;
  const int wm = (wave >> 1) << 6, wn = (wave & 1) << 6;
#pragma unroll
  for (int mi = 0; mi < 4; mi++) {
    const int gm = m0 + wm + (mi << 4) + l16;
#pragma unroll
    for (int ni = 0; ni < 4; ni++) {
      const int gn = n0 + wn + (ni << 4) + (quad << 2);
      float4 f;
      f.x = acc[mi][ni][0];
      f.y = acc[mi][ni][1];
      f.z = acc[mi][ni][2];
      f.w = acc[mi][ni][3];
      *(float4*)(out + (size_t)gm * 1024 + gn) = f;
    }
  }
}

// ---------------- fused attention: one wg per (64 q-rows, h, b) ----------------
// Q,K: [B,H,512,64] bf16.  Vt: [B,H,64,512] bf16.
// T3 2-phase pipeline: double-buffered sK/sV; stage tile j+1 before computing
// tile j; raw barrier + counted vmcnt so next-tile loads stay in flight.
// vmcnt(4) is safe for any compiler placement of the 2 bias loads: draining to
// <=4 outstanding retires bias + current-tile loads in either issue order.

__global__ __launch_bounds__(256) void attn_kernel(
    const u16* __restrict__ Qh, const u16* __restrict__ Kh,
    const u16* __restrict__ Vt, const u16* __restrict__ Bp,
    u16* __restrict__ Ob) {
  __shared__ __align__(16) u16 sQ[64 * 64];
  __shared__ __align__(16) u16 sK[2][64 * 64];
  __shared__ __align__(16) u16 sV[2][64 * 64];     // [hd][j] layout
  __shared__ __align__(16) u16 sP[4 * 16 * 72];    // stride 72 (pad vs bank conflicts)
  const int flat = blockIdx.x + (blockIdx.y << 3) + (blockIdx.z << 7);
  const int qt = (flat >> 3) & 7;
  const int h  = (flat >> 6) & 15;
  const int b  = (flat & 7) | (((flat >> 10) & 1) << 3);
  const int q0 = qt << 6;
  const int tid = threadIdx.x, wave = tid >> 6, lane = tid & 63;
  const int quad = lane >> 4, l16 = lane & 15;
  const int c0  = (quad ^ (l16 & 7)) << 3;                 // swizzled read offset
  const int swb = (((tid & 7) ^ ((tid >> 3) & 7)) << 4);   // swizzled staging byte off

  const u16* Qg = Qh + ((size_t)((b << 4) + h) * 512 + q0) * 64;
  const u16* Kg = Kh + (size_t)((b << 4) + h) * 512 * 64;
  const u16* Vg = Vt + (size_t)((b << 4) + h) * 64 * 512;
  const uint4* Bpg = (const uint4*)Bp + (((size_t)b * 8 + qt) * 8 * 256 + tid) * 2;

  // prologue: stage Q (2 loads), then K/V tile 0 (4 loads) into buf 0
#pragma unroll
  for (int i = 0; i < 2; i++) {
    const int e = (i << 8) + tid;
    gl2lds16((const char*)Qg + (e >> 3) * 128 + swb,
             (char*)sQ + (((i << 8) + (wave << 6)) << 4));
  }
#pragma unroll
  for (int i = 0; i < 2; i++) {
    const int e = (i << 8) + tid;
    gl2lds16((const char*)Kg + (e >> 3) * 128 + swb,
             (char*)sK[0] + (((i << 8) + (wave << 6)) << 4));
    gl2lds16((const char*)Vg + (size_t)(e >> 3) * 1024 + swb,
             (char*)sV[0] + (((i << 8) + (wave << 6)) << 4));
  }
  asm volatile("s_waitcnt vmcnt(4)" ::: "memory");   // Q landed; KV0 in flight
  barrier_raw();

  // Q fragments are loop-invariant: read once
  const bf8 aq0 = *(const bf8*)(sQ + ((wave << 4) + l16) * 64 + c0);
  const bf8 aq1 = *(const bf8*)(sQ + ((wave << 4) + l16) * 64 + (c0 ^ 32));

  f4 o[4];
  f4 zero = {0.f, 0.f, 0.f, 0.f};
#pragma unroll
  for (int i = 0; i < 4; i++) o[i] = zero;
  float lsum[4] = {0.f, 0.f, 0.f, 0.f};
  const int qrl = (wave << 4) + (quad << 2);

  int cur = 0;
  for (int jt = 0; jt < 8; jt++) {
    // bias chunk for this j-tile: 32B/lane (2 dwordx4, compiler-waited)
    const uint4 bc0 = Bpg[jt * 512];
    const uint4 bc1 = Bpg[jt * 512 + 1];
    const u32 bw[8] = {bc0.x, bc0.y, bc0.z, bc0.w, bc1.x, bc1.y, bc1.z, bc1.w};

    if (jt < 7) {
      // stage tile jt+1 into the other buffer (its readers finished before
      // the previous end-of-iter barrier)
      const int j1 = (jt + 1) << 6;
#pragma unroll
      for (int i = 0; i < 2; i++) {
        const int e = (i << 8) + tid;
        gl2lds16((const char*)Kg + (size_t)j1 * 128 + (e >> 3) * 128 + swb,
                 (char*)sK[cur ^ 1] + (((i << 8) + (wave << 6)) << 4));
        gl2lds16((const char*)Vg + (size_t)(e >> 3) * 1024 + j1 * 2 + swb,
                 (char*)sV[cur ^ 1] + (((i << 8) + (wave << 6)) << 4));
      }
      asm volatile("s_waitcnt vmcnt(4)" ::: "memory");  // tile jt landed
    } else {
      asm volatile("s_waitcnt vmcnt(0)" ::: "memory");  // last tile: drain
    }
    barrier_raw();   // all waves' current-tile loads landed

    const u16* kbuf = sK[cur];
    const u16* vbuf = sV[cur];
    u16* pw = sP + wave * (16 * 72);

    __builtin_amdgcn_s_setprio(1);
#pragma unroll
    for (int nb = 0; nb < 4; nb++) {
      bf8 b0 = *(const bf8*)(kbuf + ((nb << 4) + l16) * 64 + c0);
      bf8 b1 = *(const bf8*)(kbuf + ((nb << 4) + l16) * 64 + (c0 ^ 32));
      f4 s = zero;
      s = __builtin_amdgcn_mfma_f32_16x16x32_bf16(aq0, b0, s, 0, 0, 0);
      s = __builtin_amdgcn_mfma_f32_16x16x32_bf16(aq1, b1, s, 0, 0, 0);
#pragma unroll
      for (int r = 0; r < 4; r++) {
        const u32 w = bw[nb * 2 + (r >> 1)];
        const float bias = bf2f((r & 1) ? (u16)(w >> 16) : (u16)(w & 0xFFFF));
        const float ev = __expf(s[r] * 0.03125f + bias);
        lsum[r] += ev;
        pw[((quad << 2) + r) * 72 + (nb << 4) + l16] = f2bf(ev);
      }
    }
    __builtin_amdgcn_s_setprio(0);

    // P: C-layout -> LDS (per-wave region, in-wave ordering only)
    bf8 ap0 = *(const bf8*)(pw + l16 * 72 + (quad << 3));
    bf8 ap1 = *(const bf8*)(pw + l16 * 72 + 32 + (quad << 3));
    __builtin_amdgcn_s_setprio(1);
#pragma unroll
    for (int db = 0; db < 4; db++) {
      bf8 v0 = *(const bf8*)(vbuf + ((db << 4) + l16) * 64 + c0);
      bf8 v1 = *(const bf8*)(vbuf + ((db << 4) + l16) * 64 + (c0 ^ 32));
      o[db] = __builtin_amdgcn_mfma_f32_16x16x32_bf16(ap0, v0, o[db], 0, 0, 0);
      o[db] = __builtin_amdgcn_mfma_f32_16x16x32_bf16(ap1, v1, o[db], 0, 0, 0);
    }
    __builtin_amdgcn_s_setprio(0);

    barrier_raw();   // protect buf[cur] before it is re-staged next iter
    cur ^= 1;
  }

  // epilogue: reduce row sums over the 16 l16-lanes, normalize, store
#pragma unroll
  for (int r = 0; r < 4; r++) {
    float s = lsum[r];
    s += __shfl_xor(s, 1);
    s += __shfl_xor(s, 2);
    s += __shfl_xor(s, 4);
    s += __shfl_xor(s, 8);
    const float inv = 1.f / s;
    const int gr = q0 + qrl + r;
#pragma unroll
    for (int db = 0; db < 4; db++)
      Ob[(size_t)((b << 9) + gr) * 1024 + (h << 6) + (db << 4) + l16] =
          f2bf(o[db][r] * inv);
  }
}

// ---------------- launch ----------------

extern "C" void kernel_launch(void* const* d_in, const int* in_sizes, int n_in,
                              void* d_out, int out_size, void* d_ws, size_t ws_size,
                              hipStream_t stream) {
  const float* x  = (const float*)d_in[0];
  const float* sp = (const float*)d_in[1];
  const float* ed = (const float*)d_in[2];
  const float* Wq = (const float*)d_in[3];
  const float* Wk = (const float*)d_in[4];
  const float* Wv = (const float*)d_in[5];
  const float* Wo = (const float*)d_in[6];
  float* out = (float*)d_out;

  char* w = (char*)d_ws;
  u16* xb  = (u16*)(w);                  // 16 MB  : x bf16 [8192][1024]
  u16* wqb = (u16*)(w + 16777216);       // 2 MB
  u16* wkb = (u16*)(w + 18874368);
  u16* wvb = (u16*)(w + 20971520);
  u16* wob = (u16*)(w + 23068672);
  u16* Qh  = (u16*)(w + 25165824);       // 16 MB  : [B,H,512,64]
  u16* Kh  = (u16*)(w + 41943040);       // 16 MB
  u16* Vt  = (u16*)(w + 58720256);       // 16 MB  : [B,H,64,512]
  u16* Ob  = (u16*)(w + 75497472);       // 16 MB  : [8192][1024]
  u16* Bp  = (u16*)(w + 92274688);       // 8 MB   : permuted bf16(sp+ed)

  cast_bf16<<<4096, 256, 0, stream>>>(x, (uint4*)xb, 1048576);
  cast4_bf16<<<2048, 256, 0, stream>>>(Wq, Wk, Wv, Wo,
                                       (uint4*)wqb, (uint4*)wkb,
                                       (uint4*)wvb, (uint4*)wob);
  bias_perm<<<dim3(8, 8, 16), 256, 0, stream>>>(sp, ed, Bp);

  qkv_kernel<<<dim3(8, 64, 3), 256, 0, stream>>>(xb, wqb, wkb, wvb, Qh, Kh, Vt);
  attn_kernel<<<dim3(8, 16, 16), 256, 0, stream>>>(Qh, Kh, Vt, Bp, Ob);
  oproj_kernel<<<dim3(8, 64, 1), 256, 0, stream>>>(Ob, wob, out);
}

// Round 2
// 254.391 us; speedup vs baseline: 1.0389x; 1.0389x over previous
//
#include <hip/hip_runtime.h>
#include <cstdint>

// GraphormerMultiHeadAttention on MI355X (gfx950), bf16 MFMA path.
// B=16, N=512, D=1024, H=16, hd=64. scale = D^-0.5 = 1/32.
//
// R4 -> R5 changes (attn only; qkv/oproj keep the R4 transposed epilogues):
//  - attn LDS cut back to 32768 B (was 50176 -> 3 blocks/CU, the R4
//    regression). K double-buffered by REUSING the Q staging buffer (Q is
//    register-resident after the prologue); V single-buffered, staged at top
//    of iter and waited with counted vmcnt(2) right before PV (latency hides
//    under QK^T+softmax). sP: stride-72 pad -> XOR-swizzle [16][64] (reuses
//    the c0 read offset), saves 1KB. 5 blocks/CU now fit (was 4 in R3).
//  - bias prefetched one full iteration ahead into registers (+8 VGPR);
//    its wait no longer sits inside the softmax.
//  - vmcnt ledger: enter iter with K[jt] (2) in flight; issue bias+1, V,
//    K[jt+1] (pinned order via memory-clobber asm); vmcnt(6) retires K[jt];
//    vmcnt(2) after QK^T retires bias+V, K[jt+1] stays in flight.

typedef unsigned short u16;
typedef unsigned int   u32;
typedef __attribute__((ext_vector_type(8))) short bf8;   // 8 x bf16 (4 VGPRs)
typedef __attribute__((ext_vector_type(4))) float f4;    // 4 x f32 accum

__device__ __forceinline__ u16 f2bf(float x) {
  u32 u = __float_as_uint(x);
  u += 0x7FFF + ((u >> 16) & 1);        // round-to-nearest-even
  return (u16)(u >> 16);
}

__device__ __forceinline__ float bf2f(u16 x) {
  return __uint_as_float(((u32)x) << 16);
}

// async global->LDS, 16B per lane. LDS dest = wave-uniform base + lane*16.
__device__ __forceinline__ void gl2lds16(const void* g, void* l) {
  __builtin_amdgcn_global_load_lds(
      (const __attribute__((address_space(1))) u32*)g,
      (__attribute__((address_space(3))) u32*)l, 16, 0, 0);
}

// raw workgroup barrier WITHOUT the __syncthreads vmcnt(0) drain.
__device__ __forceinline__ void barrier_raw() {
  asm volatile("" ::: "memory");
  __builtin_amdgcn_s_barrier();
  asm volatile("" ::: "memory");
}

__device__ __forceinline__ void mem_pin() { asm volatile("" ::: "memory"); }

// ---------------- cast kernels ----------------

__global__ __launch_bounds__(256) void cast_bf16(const float* __restrict__ src,
                                                 uint4* __restrict__ dst, int n8) {
  const int i = blockIdx.x * 256 + threadIdx.x;
  if (i >= n8) return;
  const float4* s = (const float4*)src;
  const float4 a = s[2 * i], c = s[2 * i + 1];
  uint4 o;
  o.x = (u32)f2bf(a.x) | ((u32)f2bf(a.y) << 16);
  o.y = (u32)f2bf(a.z) | ((u32)f2bf(a.w) << 16);
  o.z = (u32)f2bf(c.x) | ((u32)f2bf(c.y) << 16);
  o.w = (u32)f2bf(c.z) | ((u32)f2bf(c.w) << 16);
  dst[i] = o;
}

// 4 weight matrices (1M elems each) in one launch: i>>17 selects the matrix.
__global__ __launch_bounds__(256) void cast4_bf16(
    const float* __restrict__ s0, const float* __restrict__ s1,
    const float* __restrict__ s2, const float* __restrict__ s3,
    uint4* __restrict__ d0, uint4* __restrict__ d1,
    uint4* __restrict__ d2, uint4* __restrict__ d3) {
  const int i = blockIdx.x * 256 + threadIdx.x;     // 0 .. 524287
  const int w = i >> 17, j = i & 131071;
  const float* src = (w == 0) ? s0 : (w == 1) ? s1 : (w == 2) ? s2 : s3;
  uint4* dst = (w == 0) ? d0 : (w == 1) ? d1 : (w == 2) ? d2 : d3;
  const float4* s = (const float4*)src;
  const float4 a = s[2 * j], c = s[2 * j + 1];
  uint4 o;
  o.x = (u32)f2bf(a.x) | ((u32)f2bf(a.y) << 16);
  o.y = (u32)f2bf(a.z) | ((u32)f2bf(a.w) << 16);
  o.z = (u32)f2bf(c.x) | ((u32)f2bf(c.y) << 16);
  o.w = (u32)f2bf(c.z) | ((u32)f2bf(c.w) << 16);
  dst[j] = o;
}

// bias = bf16(sp+ed), permuted so attn lane `tid` of block (b, qt, jt) reads
// its 16 values (4 rows x 4 col-groups) as one contiguous 32B chunk.
// chunk element order: idx = nb*4 + r  (nb = col group, r = row within quad)
__global__ __launch_bounds__(256) void bias_perm(const float* __restrict__ sp,
                                                 const float* __restrict__ ed,
                                                 u16* __restrict__ Bp) {
  const int jt = blockIdx.x, qt = blockIdx.y, b = blockIdx.z;
  const int tid = threadIdx.x;
  const int wave = tid >> 6, quad = (tid >> 4) & 3, l16 = tid & 15;
  const int qrl = (wave << 4) + (quad << 2);
  union { u16 a[16]; uint4 v[2]; } tmp;
#pragma unroll
  for (int nb = 0; nb < 4; nb++) {
    const int col = (jt << 6) + (nb << 4) + l16;
#pragma unroll
    for (int r = 0; r < 4; r++) {
      const int row = (qt << 6) + qrl + r;
      const size_t idx = ((size_t)b << 18) + (size_t)row * 512 + col;
      tmp.a[nb * 4 + r] = f2bf(sp[idx] + ed[idx]);
    }
  }
  uint4* out = (uint4*)Bp + ((((size_t)b * 8 + qt) * 8 + jt) * 256 + tid) * 2;
  out[0] = tmp.v[0];
  out[1] = tmp.v[1];
}

// ---------------- GEMM core: C(128x128) = A(128x1024) * Bt(128x1024)^T ----------------
// A row-major [M][1024], Bt row-major [Nout][1024] (computes A @ Bt^T).
// LDS tiles are [128 rows][8 chunks of 16B], slot (r,c) holds global chunk c^(r&7).
// SWAP=true computes C^T fragments (mfma(B,A)): lane&15 -> M dim, (quad,reg) -> N
// dim, so the 4 regs of each fragment are CONSECUTIVE along N -> packed stores.

template <bool SWAP>
__device__ __forceinline__ void gemm_core(const u16* __restrict__ A,
                                          const u16* __restrict__ Bt,
                                          int m0, int n0,
                                          u16* lA, u16* lB, f4 acc[4][4]) {
  const int tid  = threadIdx.x;
  const int wave = tid >> 6;
  const int lane = tid & 63;
  const int quad = lane >> 4;
  const int l16  = lane & 15;
  const int wm   = (wave >> 1) << 6;
  const int wn   = (wave & 1) << 6;
  const int srow = tid >> 3;
  const int scol = ((tid & 7) ^ (srow & 7)) << 3;   // swizzled source chunk
  const int c0   = (quad ^ (l16 & 7)) << 3;         // swizzled read offset, kk=0

  f4 zero = {0.f, 0.f, 0.f, 0.f};
#pragma unroll
  for (int mi = 0; mi < 4; mi++)
#pragma unroll
    for (int ni = 0; ni < 4; ni++) acc[mi][ni] = zero;

  const u16* Ab = A  + (size_t)(m0 + srow) * 1024 + scol;
  const u16* Bb = Bt + (size_t)(n0 + srow) * 1024 + scol;

  for (int k0 = 0; k0 < 1024; k0 += 64) {
    __syncthreads();   // protect LDS from previous iteration's readers
#pragma unroll
    for (int i = 0; i < 4; i++) {
      gl2lds16(Ab + (size_t)(i << 5) * 1024 + k0,
               (char*)lA + (((i << 8) + (wave << 6)) << 4));
      gl2lds16(Bb + (size_t)(i << 5) * 1024 + k0,
               (char*)lB + (((i << 8) + (wave << 6)) << 4));
    }
    __syncthreads();   // drains vmcnt(0) -> tiles visible
#pragma unroll
    for (int kk = 0; kk < 64; kk += 32) {
      const int o = c0 ^ kk;
      bf8 af[4], bfr[4];
#pragma unroll
      for (int mi = 0; mi < 4; mi++)
        af[mi] = *(const bf8*)(lA + (wm + (mi << 4) + l16) * 64 + o);
#pragma unroll
      for (int ni = 0; ni < 4; ni++)
        bfr[ni] = *(const bf8*)(lB + (wn + (ni << 4) + l16) * 64 + o);
#pragma unroll
      for (int mi = 0; mi < 4; mi++)
#pragma unroll
        for (int ni = 0; ni < 4; ni++) {
          if (SWAP)
            acc[mi][ni] = __builtin_amdgcn_mfma_f32_16x16x32_bf16(
                bfr[ni], af[mi], acc[mi][ni], 0, 0, 0);
          else
            acc[mi][ni] = __builtin_amdgcn_mfma_f32_16x16x32_bf16(
                af[mi], bfr[ni], acc[mi][ni], 0, 0, 0);
        }
    }
  }
}

// ---------------- QKV projection ----------------
// XCD remap: flat bits [2:0]=m_lo [5:3]=n_tile [8:6]=m_hi [10:9]=proj.

__global__ __launch_bounds__(256) void qkv_kernel(
    const u16* __restrict__ xb, const u16* __restrict__ wq,
    const u16* __restrict__ wk, const u16* __restrict__ wv,
    u16* __restrict__ Qh, u16* __restrict__ Kh, u16* __restrict__ Vt) {
  __shared__ __align__(16) u16 lA[128 * 64];
  __shared__ __align__(16) u16 lB[128 * 64];
  const int flat = blockIdx.x + (blockIdx.y << 3) + (blockIdx.z << 9);
  const int m_tile = (flat & 7) | (((flat >> 6) & 7) << 3);
  const int n_tile = (flat >> 3) & 7;
  const int proj = flat >> 9;
  const int m0 = m_tile << 7, n0 = n_tile << 7;
  const u16* W = (proj == 0) ? wq : (proj == 1) ? wk : wv;

  const int tid = threadIdx.x, wave = tid >> 6, lane = tid & 63;
  const int quad = lane >> 4, l16 = lane & 15;
  const int wm = (wave >> 1) << 6, wn = (wave & 1) << 6;
  f4 acc[4][4];

  if (proj == 2) {
    // V: normal orientation; C rows (quad,reg) = tokens, which are the
    // contiguous dim of Vt [B,H,hd,512] -> ushort4 over 4 consecutive n.
    gemm_core<false>(xb, W, m0, n0, lA, lB, acc);
#pragma unroll
    for (int mi = 0; mi < 4; mi++) {
      const int gmb = m0 + wm + (mi << 4) + (quad << 2);
      const int b = gmb >> 9, nb = gmb & 511;
#pragma unroll
      for (int ni = 0; ni < 4; ni++) {
        const int gn = n0 + wn + (ni << 4) + l16;
        const int h = gn >> 6, hdi = gn & 63;
        ushort4 pk;
        pk.x = f2bf(acc[mi][ni][0]);
        pk.y = f2bf(acc[mi][ni][1]);
        pk.z = f2bf(acc[mi][ni][2]);
        pk.w = f2bf(acc[mi][ni][3]);
        *(ushort4*)(Vt + ((size_t)((b << 4) + h) * 64 + hdi) * 512 + nb) = pk;
      }
    }
  } else {
    // Q/K: transposed fragments; (quad,reg) = hd (contiguous in Qh/Kh),
    // lane&15 = token row -> one ushort4 per fragment.
    gemm_core<true>(xb, W, m0, n0, lA, lB, acc);
    u16* dst = (proj == 0) ? Qh : Kh;
#pragma unroll
    for (int mi = 0; mi < 4; mi++) {
      const int gm = m0 + wm + (mi << 4) + l16;      // token row
      const int b = gm >> 9, n = gm & 511;
#pragma unroll
      for (int ni = 0; ni < 4; ni++) {
        const int gn = n0 + wn + (ni << 4) + (quad << 2);  // hd dim
        const int h = gn >> 6, hdi = gn & 63;
        ushort4 pk;
        pk.x = f2bf(acc[mi][ni][0]);
        pk.y = f2bf(acc[mi][ni][1]);
        pk.z = f2bf(acc[mi][ni][2]);
        pk.w = f2bf(acc[mi][ni][3]);
        *(ushort4*)(dst + ((size_t)((b << 4) + h) * 512 + n) * 64 + hdi) = pk;
      }
    }
  }
}

// ---------------- output projection ----------------
// XCD remap: flat bits [2:0]=m_lo [5:3]=n_tile [8:6]=m_hi.
// Transposed fragments -> float4 stores (gn contiguous).

__global__ __launch_bounds__(256) void oproj_kernel(const u16* __restrict__ Ob,
                                                    const u16* __restrict__ wo,
                                                    float* __restrict__ out) {
  __shared__ __align__(16) u16 lA[128 * 64];
  __shared__ __align__(16) u16 lB[128 * 64];
  const int flat = blockIdx.x + (blockIdx.y << 3);
  const int m0 = ((flat & 7) | (((flat >> 6) & 7) << 3)) << 7;
  const int n0 = ((flat >> 3) & 7) << 7;
  f4 acc[4][4];
  gemm_core<true>(Ob, wo, m0, n0, lA, lB, acc);

  const int tid = threadIdx.x, wave = tid >> 6, lane = tid & 63;
  const int quad = lane >> 4, l16 = lane & 15;
  const int wm = (wave >> 1) << 6, wn = (wave & 1) << 6;
#pragma unroll
  for (int mi = 0; mi < 4; mi++) {
    const int gm = m0 + wm + (mi << 4) + l16;
#pragma unroll
    for (int ni = 0; ni < 4; ni++) {
      const int gn = n0 + wn + (ni << 4) + (quad << 2);
      float4 f;
      f.x = acc[mi][ni][0];
      f.y = acc[mi][ni][1];
      f.z = acc[mi][ni][2];
      f.w = acc[mi][ni][3];
      *(float4*)(out + (size_t)gm * 1024 + gn) = f;
    }
  }
}

// ---------------- fused attention: one wg per (64 q-rows, h, b) ----------------
// Q,K: [B,H,512,64] bf16.  Vt: [B,H,64,512] bf16.
// LDS 32768 B total: sK0 + sK1 (K double buffer; sK1 doubles as the Q staging
// area during the prologue) + sV (single) + sP (XOR-swizzled [4][16][64]).
// Pipeline per iter jt (entering with K[jt] 2 loads in flight):
//   issue bias[jt+1] -> regs | V[jt] -> sV | K[jt+1] -> knxt   (order pinned)
//   vmcnt(6) [K[jt] landed] ; barrier A ; QK^T + softmax -> sP
//   vmcnt(2) [V landed, K[jt+1] stays in flight] ; barrier B ; PV
//   barrier C [sV/knxt free for next iter]

__global__ __launch_bounds__(256) void attn_kernel(
    const u16* __restrict__ Qh, const u16* __restrict__ Kh,
    const u16* __restrict__ Vt, const u16* __restrict__ Bp,
    u16* __restrict__ Ob) {
  __shared__ __align__(16) u16 sK0[64 * 64];
  __shared__ __align__(16) u16 sK1[64 * 64];   // Q staging area, then K odd buf
  __shared__ __align__(16) u16 sV[64 * 64];    // [hd][j] layout
  __shared__ __align__(16) u16 sP[4 * 16 * 64]; // per-wave [16][64], XOR-swizzled
  const int flat = blockIdx.x + (blockIdx.y << 3) + (blockIdx.z << 7);
  const int qt = (flat >> 3) & 7;
  const int h  = (flat >> 6) & 15;
  const int b  = (flat & 7) | (((flat >> 10) & 1) << 3);
  const int q0 = qt << 6;
  const int tid = threadIdx.x, wave = tid >> 6, lane = tid & 63;
  const int quad = lane >> 4, l16 = lane & 15;
  const int c0  = (quad ^ (l16 & 7)) << 3;                 // swizzled read offset
  const int swb = (((tid & 7) ^ ((tid >> 3) & 7)) << 4);   // swizzled staging byte off

  const u16* Qg = Qh + ((size_t)((b << 4) + h) * 512 + q0) * 64;
  const u16* Kg = Kh + (size_t)((b << 4) + h) * 512 * 64;
  const u16* Vg = Vt + (size_t)((b << 4) + h) * 64 * 512;
  const uint4* Bpg = (const uint4*)Bp + (((size_t)b * 8 + qt) * 8 * 256 + tid) * 2;

  // prologue: Q -> sK1 (2 loads), K0 -> sK0 (2 loads), then bias[0] to regs
#pragma unroll
  for (int i = 0; i < 2; i++) {
    const int e = (i << 8) + tid;
    gl2lds16((const char*)Qg + (e >> 3) * 128 + swb,
             (char*)sK1 + (((i << 8) + (wave << 6)) << 4));
  }
#pragma unroll
  for (int i = 0; i < 2; i++) {
    const int e = (i << 8) + tid;
    gl2lds16((const char*)Kg + (e >> 3) * 128 + swb,
             (char*)sK0 + (((i << 8) + (wave << 6)) << 4));
  }
  mem_pin();
  uint4 cb0 = Bpg[0];
  uint4 cb1 = Bpg[1];
  mem_pin();
  asm volatile("s_waitcnt vmcnt(4)" ::: "memory");   // Q landed; K0+bias in flight
  barrier_raw();

  // Q fragments -> registers; then sK1 is dead and becomes the K odd buffer
  const bf8 aq0 = *(const bf8*)(sK1 + ((wave << 4) + l16) * 64 + c0);
  const bf8 aq1 = *(const bf8*)(sK1 + ((wave << 4) + l16) * 64 + (c0 ^ 32));
  asm volatile("s_waitcnt lgkmcnt(0)" ::: "memory"); // Q reads complete
  barrier_raw();                                     // all waves done with sK1

  f4 o[4];
  f4 zero = {0.f, 0.f, 0.f, 0.f};
#pragma unroll
  for (int i = 0; i < 4; i++) o[i] = zero;
  float lsum[4] = {0.f, 0.f, 0.f, 0.f};
  const int qrl = (wave << 4) + (quad << 2);
  u16* pw = sP + wave * 1024;                        // per-wave [16][64]

  for (int jt = 0; jt < 8; jt++) {
    const u16* kcur = (jt & 1) ? sK1 : sK0;
    u16* knxt = (jt & 1) ? sK0 : sK1;

    // bias prefetch for jt+1 (oldest of this iter's issues)
    uint4 nb0 = cb0, nb1 = cb1;
    if (jt < 7) {
      nb0 = Bpg[(jt + 1) * 512];
      nb1 = Bpg[(jt + 1) * 512 + 1];
    }
    mem_pin();
    // stage V[jt] -> sV (readers of old sV finished before barrier C)
#pragma unroll
    for (int i = 0; i < 2; i++) {
      const int e = (i << 8) + tid;
      gl2lds16((const char*)Vg + (size_t)(e >> 3) * 1024 + (jt << 6) * 2 + swb,
               (char*)sV + (((i << 8) + (wave << 6)) << 4));
    }
    // stage K[jt+1] -> knxt (readers finished before prev iter's barrier B)
    if (jt < 7) {
      const int j1 = (jt + 1) << 6;
#pragma unroll
      for (int i = 0; i < 2; i++) {
        const int e = (i << 8) + tid;
        gl2lds16((const char*)Kg + (size_t)j1 * 128 + (e >> 3) * 128 + swb,
                 (char*)knxt + (((i << 8) + (wave << 6)) << 4));
      }
    }
    mem_pin();
    // retire K[jt] (the 2 oldest); bias/V/K[jt+1] stay in flight
    if (jt < 7)
      asm volatile("s_waitcnt vmcnt(6)" ::: "memory");
    else
      asm volatile("s_waitcnt vmcnt(2)" ::: "memory");
    barrier_raw();   // A: K[jt] visible to all waves

    const u32 bw[8] = {cb0.x, cb0.y, cb0.z, cb0.w, cb1.x, cb1.y, cb1.z, cb1.w};

    __builtin_amdgcn_s_setprio(1);
#pragma unroll
    for (int nb = 0; nb < 4; nb++) {
      bf8 b0 = *(const bf8*)(kcur + ((nb << 4) + l16) * 64 + c0);
      bf8 b1 = *(const bf8*)(kcur + ((nb << 4) + l16) * 64 + (c0 ^ 32));
      f4 s = zero;
      s = __builtin_amdgcn_mfma_f32_16x16x32_bf16(aq0, b0, s, 0, 0, 0);
      s = __builtin_amdgcn_mfma_f32_16x16x32_bf16(aq1, b1, s, 0, 0, 0);
#pragma unroll
      for (int r = 0; r < 4; r++) {
        const u32 w = bw[nb * 2 + (r >> 1)];
        const float bias = bf2f((r & 1) ? (u16)(w >> 16) : (u16)(w & 0xFFFF));
        const float ev = __expf(s[r] * 0.03125f + bias);
        lsum[r] += ev;
        // sP row=(quad*4+r), col=(nb*16+l16); chunk XOR-swizzled by row&7
        const int row = (quad << 2) + r;
        const int swc = (((nb << 1) + (l16 >> 3)) ^ (row & 7)) << 3;
        pw[row * 64 + swc + (l16 & 7)] = f2bf(ev);
      }
    }
    __builtin_amdgcn_s_setprio(0);

    // retire V (and bias prefetch); K[jt+1] stays in flight across barrier B
    if (jt < 7)
      asm volatile("s_waitcnt vmcnt(2)" ::: "memory");
    else
      asm volatile("s_waitcnt vmcnt(0)" ::: "memory");
    barrier_raw();   // B: V visible to all waves

    // P fragments: row=l16, chunks quad / quad+4 -> same c0 swizzle
    bf8 ap0 = *(const bf8*)(pw + l16 * 64 + c0);
    bf8 ap1 = *(const bf8*)(pw + l16 * 64 + (c0 ^ 32));
    __builtin_amdgcn_s_setprio(1);
#pragma unroll
    for (int db = 0; db < 4; db++) {
      bf8 v0 = *(const bf8*)(sV + ((db << 4) + l16) * 64 + c0);
      bf8 v1 = *(const bf8*)(sV + ((db << 4) + l16) * 64 + (c0 ^ 32));
      o[db] = __builtin_amdgcn_mfma_f32_16x16x32_bf16(ap0, v0, o[db], 0, 0, 0);
      o[db] = __builtin_amdgcn_mfma_f32_16x16x32_bf16(ap1, v1, o[db], 0, 0, 0);
    }
    __builtin_amdgcn_s_setprio(0);

    barrier_raw();   // C: sV + knxt reader-free for next iteration
    cb0 = nb0;
    cb1 = nb1;
  }

  // epilogue: reduce row sums over the 16 l16-lanes, normalize, store
#pragma unroll
  for (int r = 0; r < 4; r++) {
    float s = lsum[r];
    s += __shfl_xor(s, 1);
    s += __shfl_xor(s, 2);
    s += __shfl_xor(s, 4);
    s += __shfl_xor(s, 8);
    const float inv = 1.f / s;
    const int gr = q0 + qrl + r;
#pragma unroll
    for (int db = 0; db < 4; db++)
      Ob[(size_t)((b << 9) + gr) * 1024 + (h << 6) + (db << 4) + l16] =
          f2bf(o[db][r] * inv);
  }
}

// ---------------- launch ----------------

extern "C" void kernel_launch(void* const* d_in, const int* in_sizes, int n_in,
                              void* d_out, int out_size, void* d_ws, size_t ws_size,
                              hipStream_t stream) {
  const float* x  = (const float*)d_in[0];
  const float* sp = (const float*)d_in[1];
  const float* ed = (const float*)d_in[2];
  const float* Wq = (const float*)d_in[3];
  const float* Wk = (const float*)d_in[4];
  const float* Wv = (const float*)d_in[5];
  const float* Wo = (const float*)d_in[6];
  float* out = (float*)d_out;

  char* w = (char*)d_ws;
  u16* xb  = (u16*)(w);                  // 16 MB  : x bf16 [8192][1024]
  u16* wqb = (u16*)(w + 16777216);       // 2 MB
  u16* wkb = (u16*)(w + 18874368);
  u16* wvb = (u16*)(w + 20971520);
  u16* wob = (u16*)(w + 23068672);
  u16* Qh  = (u16*)(w + 25165824);       // 16 MB  : [B,H,512,64]
  u16* Kh  = (u16*)(w + 41943040);       // 16 MB
  u16* Vt  = (u16*)(w + 58720256);       // 16 MB  : [B,H,64,512]
  u16* Ob  = (u16*)(w + 75497472);       // 16 MB  : [8192][1024]
  u16* Bp  = (u16*)(w + 92274688);       // 8 MB   : permuted bf16(sp+ed)

  cast_bf16<<<4096, 256, 0, stream>>>(x, (uint4*)xb, 1048576);
  cast4_bf16<<<2048, 256, 0, stream>>>(Wq, Wk, Wv, Wo,
                                       (uint4*)wqb, (uint4*)wkb,
                                       (uint4*)wvb, (uint4*)wob);
  bias_perm<<<dim3(8, 8, 16), 256, 0, stream>>>(sp, ed, Bp);

  qkv_kernel<<<dim3(8, 64, 3), 256, 0, stream>>>(xb, wqb, wkb, wvb, Qh, Kh, Vt);
  attn_kernel<<<dim3(8, 16, 16), 256, 0, stream>>>(Qh, Kh, Vt, Bp, Ob);
  oproj_kernel<<<dim3(8, 64, 1), 256, 0, stream>>>(Ob, wob, out);
}